// Round 1
// baseline (101.703 us; speedup 1.0000x reference)
//
#include <hip/hip_runtime.h>
#include <math.h>

// Problem constants (fixed by setup_inputs in the reference)
#define N_  4
#define A_  3
#define S_  13
#define NC_ 80
#define NM_ 32
#define G_  16
#define H_  104
#define W_  104
#define CH_ (5 + NC_ + NM_)   // 117
#define HW_ (H_ * W_)

// Accumulator layout in d_ws: 10 float accumulators, each on its own 128B line
// 0 n_obj, 1 n_noobj, 2 noobj_bce, 3 obj_bce, 4 xy_bce, 5 wh_mse,
// 6 one_minus_giou, 7 nll, 8 seg_mean, 9 n_valid
#define STR 32   // floats between accumulators (128 B)

__device__ __forceinline__ float bce_logits(float x, float z) {
    return fmaxf(x, 0.0f) - x * z + log1pf(expf(-fabsf(x)));
}

__device__ __forceinline__ float sigmoidf(float x) {
    return 1.0f / (1.0f + expf(-x));
}

__device__ __forceinline__ float giou_fn(float cx1, float cy1, float w1, float h1,
                                         float cx2, float cy2, float w2, float h2) {
    const float eps = 1e-9f;
    float b1x1 = cx1 - w1 * 0.5f, b1y1 = cy1 - h1 * 0.5f;
    float b1x2 = cx1 + w1 * 0.5f, b1y2 = cy1 + h1 * 0.5f;
    float b2x1 = cx2 - w2 * 0.5f, b2y1 = cy2 - h2 * 0.5f;
    float b2x2 = cx2 + w2 * 0.5f, b2y2 = cy2 + h2 * 0.5f;
    float a1 = fmaxf(b1x2 - b1x1, 0.0f) * fmaxf(b1y2 - b1y1, 0.0f) + eps;
    float a2 = fmaxf(b2x2 - b2x1, 0.0f) * fmaxf(b2y2 - b2y1, 0.0f) + eps;
    float iw = fmaxf(fminf(b1x2, b2x2) - fmaxf(b1x1, b2x1), 0.0f);
    float ih = fmaxf(fminf(b1y2, b2y2) - fmaxf(b1y1, b2y1), 0.0f);
    float inter = iw * ih + eps;
    float uni   = a1 + a2 - inter + eps;
    float iou   = inter / uni;
    float cw = fmaxf(b1x2, b2x2) - fminf(b1x1, b2x1);
    float ch = fmaxf(b1y2, b2y2) - fminf(b1y1, b2y1);
    float carea = cw * ch + eps;
    return iou - (carea - uni) / carea;
}

// One block per grid cell (n,a,i,j). 256 threads.
__global__ __launch_bounds__(256) void yolo_cell_kernel(
    const float* __restrict__ preds,    // (N,A,S,S,117)
    const float* __restrict__ target,   // (N,A,S,S,7)
    const float* __restrict__ anchors,  // (A,2)
    const float* __restrict__ protos,   // (N,32,H,W)
    const float* __restrict__ masks,    // (N,16,H,W)
    float* __restrict__ acc)
{
    const int cell = blockIdx.x;
    const int j = cell % S_;
    const int i = (cell / S_) % S_;
    const int a = (cell / (S_ * S_)) % A_;
    const int n = cell / (A_ * S_ * S_);
    const int tid = threadIdx.x;

    const float* p = preds  + (size_t)cell * CH_;
    const float* t = target + (size_t)cell * 7;

    __shared__ float s_tc[NM_];
    __shared__ float s_red[256];

    // conf_t is exactly 0.0 or 1.0; uniform load -> uniform branching
    const float conf_t = t[4];
    const bool obj = (conf_t == 1.0f);

    // ---- thread 0: conf / box losses -------------------------------------
    if (tid == 0) {
        float x = p[4];  // conf logit
        if (conf_t == 0.0f) {
            atomicAdd(&acc[1 * STR], 1.0f);
            atomicAdd(&acc[2 * STR], bce_logits(x, 0.0f));
        }
        if (obj) {
            float tx = t[0], ty = t[1], tw = t[2], th = t[3];
            float aw = anchors[a * 2 + 0], ah = anchors[a * 2 + 1];
            float sx = sigmoidf(p[0]);
            float sy = sigmoidf(p[1]);
            float pw = expf(p[2]) * aw;
            float ph = expf(p[3]) * ah;
            float giou = giou_fn(sx, sy, pw, ph, tx, ty, tw, th);
            atomicAdd(&acc[0 * STR], 1.0f);
            atomicAdd(&acc[3 * STR], bce_logits(x, fmaxf(giou, 0.0f)));
            atomicAdd(&acc[4 * STR], bce_logits(sx, tx) + bce_logits(sy, ty));
            float twl = logf(1e-16f + tw / aw);
            float thl = logf(1e-16f + th / ah);
            float dw = p[2] - twl, dh = p[3] - thl;
            atomicAdd(&acc[5 * STR], dw * dw + dh * dh);
            atomicAdd(&acc[6 * STR], 1.0f - giou);
        }
    }

    // ---- wave 1 (tids 64..127): class log-softmax NLL (obj cells only) ----
    if (obj && tid >= 64 && tid < 128) {
        int lane = tid - 64;
        float v0 = (lane      < NC_) ? p[5 + lane]      : -1e30f;
        float v1 = (lane + 64 < NC_) ? p[5 + lane + 64] : -1e30f;
        float mx = fmaxf(v0, v1);
        for (int o = 32; o > 0; o >>= 1) mx = fmaxf(mx, __shfl_xor(mx, o, 64));
        float se = ((lane      < NC_) ? expf(v0 - mx) : 0.0f)
                 + ((lane + 64 < NC_) ? expf(v1 - mx) : 0.0f);
        for (int o = 32; o > 0; o >>= 1) se += __shfl_xor(se, o, 64);
        if (lane == 0) {
            int label = (int)t[5];
            float lse = mx + logf(se);
            atomicAdd(&acc[7 * STR], lse - p[5 + label]);
        }
    }

    // ---- whole block: masked-region segmentation BCE (obj cells only) -----
    if (obj) {
        // region bounds (uniform across block)
        float tx = t[0], ty = t[1], tw = t[2], th = t[3];
        float bx = (tx + (float)j) * ((float)W_ / (float)S_);
        float by = (ty + (float)i) * ((float)H_ / (float)S_);
        float bw = tw * ((float)W_ / (float)S_);
        float bh = th * ((float)H_ / (float)S_);
        int x1 = (int)floorf(bx - bw * 0.5f);
        int x2 = (int)floorf(bx + bw * 0.5f);
        int y1 = (int)floorf(by - bh * 0.5f);
        int y2 = (int)floorf(by + bh * 0.5f);
        int lox = max(x1, 0), hix = min(x2, W_);
        int loy = max(y1, 0), hiy = min(y2, H_);
        int ncols = max(hix - lox, 0);
        int nrows = max(hiy - loy, 0);
        int area = nrows * ncols;

        // stage tanh(coeffs) in LDS
        if (tid < NM_) s_tc[tid] = tanhf(p[5 + NC_ + tid]);
        __syncthreads();

        float lsum = 0.0f;
        if (area > 0) {
            int id = (int)t[6];
            id = min(max(id, 0), G_ - 1);
            const float* tm = masks  + ((size_t)(n * G_ + id)) * HW_;
            const float* pr = protos + (size_t)n * NM_ * HW_;
            for (int px = tid; px < area; px += 256) {
                int h = loy + px / ncols;
                int w = lox + px % ncols;
                int off = h * W_ + w;
                float inst = 0.0f;
#pragma unroll
                for (int m = 0; m < NM_; ++m)
                    inst += s_tc[m] * pr[m * HW_ + off];
                lsum += bce_logits(inst, tm[off]);
            }
        }

        // block tree-reduce
        s_red[tid] = lsum;
        __syncthreads();
        for (int s = 128; s > 0; s >>= 1) {
            if (tid < s) s_red[tid] += s_red[tid + s];
            __syncthreads();
        }
        if (tid == 0 && area > 0) {
            float seg_mean = s_red[0] / fmaxf((float)area, 1.0f);
            atomicAdd(&acc[8 * STR], seg_mean);
            atomicAdd(&acc[9 * STR], 1.0f);
        }
    }
}

__global__ void yolo_finalize_kernel(const float* __restrict__ acc,
                                     float* __restrict__ out)
{
    if (threadIdx.x == 0 && blockIdx.x == 0) {
        float n_obj   = acc[0 * STR];
        float n_noobj = acc[1 * STR];
        float noobj_loss = acc[2 * STR] / n_noobj;
        float obj_loss   = acc[3 * STR] / n_obj;
        float xy_bce     = acc[4 * STR] / (n_obj * 2.0f);
        float wh_mse     = acc[5 * STR] / (n_obj * 2.0f);
        float box_loss   = xy_bce + wh_mse + acc[6 * STR] / n_obj;
        float class_loss = acc[7 * STR] / n_obj;
        float seg_loss   = acc[8 * STR] / (acc[9 * STR] + 1e-9f);
        float box_l   = 8.0f * box_loss;
        float obj_l   = 2.0f * obj_loss;
        float noobj_l = 4.0f * noobj_loss;
        float cls_l   = 1.0f * class_loss;
        float seg_l   = 10.0f * seg_loss;
        out[0] = box_l;
        out[1] = obj_l;
        out[2] = noobj_l;
        out[3] = cls_l;
        out[4] = seg_l;
        out[5] = box_l + obj_l + noobj_l + cls_l + seg_l;
    }
}

extern "C" void kernel_launch(void* const* d_in, const int* in_sizes, int n_in,
                              void* d_out, int out_size, void* d_ws, size_t ws_size,
                              hipStream_t stream) {
    const float* preds   = (const float*)d_in[0];
    const float* target  = (const float*)d_in[1];
    const float* anchors = (const float*)d_in[2];
    const float* protos  = (const float*)d_in[3];
    const float* masks   = (const float*)d_in[4];
    // d_in[5] = num_classes (80), d_in[6] = num_masks (32) — hard-coded above.

    float* acc = (float*)d_ws;
    float* out = (float*)d_out;

    // zero the 10 padded accumulators (d_ws is re-poisoned 0xAA before each call)
    hipMemsetAsync(d_ws, 0, 10 * STR * sizeof(float), stream);

    const int ncells = N_ * A_ * S_ * S_;  // 2028
    yolo_cell_kernel<<<ncells, 256, 0, stream>>>(preds, target, anchors,
                                                 protos, masks, acc);
    yolo_finalize_kernel<<<1, 64, 0, stream>>>(acc, out);
}

// Round 2
// 100.725 us; speedup vs baseline: 1.0097x; 1.0097x over previous
//
#include <hip/hip_runtime.h>
#include <math.h>

// Problem constants (fixed by setup_inputs in the reference)
#define N_  4
#define A_  3
#define S_  13
#define NC_ 80
#define NM_ 32
#define G_  16
#define H_  104
#define W_  104
#define CH_ (5 + NC_ + NM_)   // 117
#define HW_ (H_ * W_)
#define NCELL (N_ * A_ * S_ * S_)  // 2028

// d_ws layout (floats), each accumulator on its own 128B line (STR floats):
// 0 n_obj, 1 n_noobj, 2 noobj_bce, 3 obj_bce, 4 xy_bce, 5 wh_mse,
// 6 one_minus_giou, 7 nll, 8 seg_sum
// [10*STR] : int valid_cnt
// [11*STR ...] : int valid_list (capacity NCELL)
#define STR 32

__device__ __forceinline__ float bce_logits(float x, float z) {
    return fmaxf(x, 0.0f) - x * z + log1pf(expf(-fabsf(x)));
}

__device__ __forceinline__ float sigmoidf(float x) {
    return 1.0f / (1.0f + expf(-x));
}

__device__ __forceinline__ float giou_fn(float cx1, float cy1, float w1, float h1,
                                         float cx2, float cy2, float w2, float h2) {
    const float eps = 1e-9f;
    float b1x1 = cx1 - w1 * 0.5f, b1y1 = cy1 - h1 * 0.5f;
    float b1x2 = cx1 + w1 * 0.5f, b1y2 = cy1 + h1 * 0.5f;
    float b2x1 = cx2 - w2 * 0.5f, b2y1 = cy2 - h2 * 0.5f;
    float b2x2 = cx2 + w2 * 0.5f, b2y2 = cy2 + h2 * 0.5f;
    float a1 = fmaxf(b1x2 - b1x1, 0.0f) * fmaxf(b1y2 - b1y1, 0.0f) + eps;
    float a2 = fmaxf(b2x2 - b2x1, 0.0f) * fmaxf(b2y2 - b2y1, 0.0f) + eps;
    float iw = fmaxf(fminf(b1x2, b2x2) - fmaxf(b1x1, b2x1), 0.0f);
    float ih = fmaxf(fminf(b1y2, b2y2) - fmaxf(b1y1, b2y1), 0.0f);
    float inter = iw * ih + eps;
    float uni   = a1 + a2 - inter + eps;
    float iou   = inter / uni;
    float cw = fmaxf(b1x2, b2x2) - fminf(b1x1, b2x1);
    float ch = fmaxf(b1y2, b2y2) - fminf(b1y1, b2y1);
    float carea = cw * ch + eps;
    return iou - (carea - uni) / carea;
}

// ---------------------------------------------------------------------------
// Kernel A: one THREAD per cell. 8 blocks x 256. All scalar losses +
// compaction of valid (obj & area>0) cells. Wave-shuffle reduction ->
// ~256 total atomics spread over 8 addresses (no contention storm).
// ---------------------------------------------------------------------------
__global__ __launch_bounds__(256) void yolo_cell_kernel(
    const float* __restrict__ preds,    // (N,A,S,S,117)
    const float* __restrict__ target,   // (N,A,S,S,7)
    const float* __restrict__ anchors,  // (A,2)
    float* __restrict__ acc,
    int* __restrict__ valid_cnt,
    int* __restrict__ valid_list)
{
    const int tid  = threadIdx.x;
    const int cell = blockIdx.x * 256 + tid;
    const bool active = (cell < NCELL);

    float v_nobj = 0.0f, v_nnoobj = 0.0f, v_noobjbce = 0.0f, v_objbce = 0.0f;
    float v_xy = 0.0f, v_wh = 0.0f, v_g = 0.0f, v_nll = 0.0f;

    if (active) {
        const int j = cell % S_;
        const int i = (cell / S_) % S_;
        const int a = (cell / (S_ * S_)) % A_;

        const float* t = target + (size_t)cell * 7;
        const float* p = preds  + (size_t)cell * CH_;

        const float conf_t = t[4];
        const float x = p[4];  // conf logit

        if (conf_t == 0.0f) {
            v_nnoobj   = 1.0f;
            v_noobjbce = bce_logits(x, 0.0f);
        } else if (conf_t == 1.0f) {
            v_nobj = 1.0f;
            float tx = t[0], ty = t[1], tw = t[2], th = t[3];
            float aw = anchors[a * 2 + 0], ah = anchors[a * 2 + 1];
            float sx = sigmoidf(p[0]);
            float sy = sigmoidf(p[1]);
            float pw = expf(p[2]) * aw;
            float ph = expf(p[3]) * ah;
            float giou = giou_fn(sx, sy, pw, ph, tx, ty, tw, th);
            v_objbce = bce_logits(x, fmaxf(giou, 0.0f));
            v_xy     = bce_logits(sx, tx) + bce_logits(sy, ty);
            float twl = logf(1e-16f + tw / aw);
            float thl = logf(1e-16f + th / ah);
            float dw = p[2] - twl, dh = p[3] - thl;
            v_wh = dw * dw + dh * dh;
            v_g  = 1.0f - giou;

            // ---- class NLL (80-way log-softmax), serial per obj thread ----
            float mx = -1e30f;
            #pragma unroll 8
            for (int c = 0; c < NC_; ++c) mx = fmaxf(mx, p[5 + c]);
            float se = 0.0f;
            #pragma unroll 8
            for (int c = 0; c < NC_; ++c) se += expf(p[5 + c] - mx);
            int label = (int)t[5];
            v_nll = (mx + logf(se)) - p[5 + label];

            // ---- region area / compaction for the seg kernel --------------
            float bx = (tx + (float)j) * ((float)W_ / (float)S_);
            float by = (ty + (float)i) * ((float)H_ / (float)S_);
            float bw = tw * ((float)W_ / (float)S_);
            float bh = th * ((float)H_ / (float)S_);
            int x1 = (int)floorf(bx - bw * 0.5f);
            int x2 = (int)floorf(bx + bw * 0.5f);
            int y1 = (int)floorf(by - bh * 0.5f);
            int y2 = (int)floorf(by + bh * 0.5f);
            int ncols = max(min(x2, W_) - max(x1, 0), 0);
            int nrows = max(min(y2, H_) - max(y1, 0), 0);
            if (nrows * ncols > 0) {
                int slot = atomicAdd(valid_cnt, 1);
                valid_list[slot] = cell;
            }
        }
    }

    // ---- wave-level shuffle reduction (all 64 lanes participate) ----------
    #pragma unroll
    for (int o = 32; o > 0; o >>= 1) {
        v_nobj     += __shfl_xor(v_nobj,     o, 64);
        v_nnoobj   += __shfl_xor(v_nnoobj,   o, 64);
        v_noobjbce += __shfl_xor(v_noobjbce, o, 64);
        v_objbce   += __shfl_xor(v_objbce,   o, 64);
        v_xy       += __shfl_xor(v_xy,       o, 64);
        v_wh       += __shfl_xor(v_wh,       o, 64);
        v_g        += __shfl_xor(v_g,        o, 64);
        v_nll      += __shfl_xor(v_nll,      o, 64);
    }
    if ((tid & 63) == 0) {
        atomicAdd(&acc[0 * STR], v_nobj);
        atomicAdd(&acc[1 * STR], v_nnoobj);
        atomicAdd(&acc[2 * STR], v_noobjbce);
        atomicAdd(&acc[3 * STR], v_objbce);
        atomicAdd(&acc[4 * STR], v_xy);
        atomicAdd(&acc[5 * STR], v_wh);
        atomicAdd(&acc[6 * STR], v_g);
        atomicAdd(&acc[7 * STR], v_nll);
    }
}

// ---------------------------------------------------------------------------
// Kernel B: masked-region segmentation BCE over the compacted valid list.
// Persistent blocks grid-stride the list (count is data-dependent but the
// data is fixed per harness run; grid is static).
// ---------------------------------------------------------------------------
#define SEG_BLOCKS 64
__global__ __launch_bounds__(256) void yolo_seg_kernel(
    const float* __restrict__ preds,
    const float* __restrict__ target,
    const float* __restrict__ protos,   // (N,32,H,W)
    const float* __restrict__ masks,    // (N,16,H,W)
    const int* __restrict__ valid_cnt,
    const int* __restrict__ valid_list,
    float* __restrict__ acc)
{
    __shared__ float s_tc[NM_];
    __shared__ float s_red[4];
    const int tid = threadIdx.x;
    const int count = *valid_cnt;

    for (int idx = blockIdx.x; idx < count; idx += SEG_BLOCKS) {
        const int cell = valid_list[idx];
        const int j = cell % S_;
        const int i = (cell / S_) % S_;
        const int n = cell / (A_ * S_ * S_);
        const float* t = target + (size_t)cell * 7;
        const float* p = preds  + (size_t)cell * CH_;

        // region bounds (uniform across block)
        float tx = t[0], ty = t[1], tw = t[2], th = t[3];
        float bx = (tx + (float)j) * ((float)W_ / (float)S_);
        float by = (ty + (float)i) * ((float)H_ / (float)S_);
        float bw = tw * ((float)W_ / (float)S_);
        float bh = th * ((float)H_ / (float)S_);
        int x1 = (int)floorf(bx - bw * 0.5f);
        int x2 = (int)floorf(bx + bw * 0.5f);
        int y1 = (int)floorf(by - bh * 0.5f);
        int y2 = (int)floorf(by + bh * 0.5f);
        int lox = max(x1, 0), hix = min(x2, W_);
        int loy = max(y1, 0), hiy = min(y2, H_);
        int ncols = hix - lox;
        int area  = (hiy - loy) * ncols;   // >0 guaranteed by compaction

        if (tid < NM_) s_tc[tid] = tanhf(p[5 + NC_ + tid]);
        __syncthreads();

        int id = (int)t[6];
        id = min(max(id, 0), G_ - 1);
        const float* tm = masks  + ((size_t)(n * G_ + id)) * HW_;
        const float* pr = protos + (size_t)n * NM_ * HW_;

        float lsum = 0.0f;
        for (int px = tid; px < area; px += 256) {
            int h = loy + px / ncols;
            int w = lox + px % ncols;
            int off = h * W_ + w;
            float inst = 0.0f;
            #pragma unroll
            for (int m = 0; m < NM_; ++m)
                inst += s_tc[m] * pr[m * HW_ + off];
            lsum += bce_logits(inst, tm[off]);
        }

        // wave reduce then cross-wave via tiny LDS
        #pragma unroll
        for (int o = 32; o > 0; o >>= 1) lsum += __shfl_xor(lsum, o, 64);
        if ((tid & 63) == 0) s_red[tid >> 6] = lsum;
        __syncthreads();
        if (tid == 0) {
            float tot = s_red[0] + s_red[1] + s_red[2] + s_red[3];
            atomicAdd(&acc[8 * STR], tot / fmaxf((float)area, 1.0f));
        }
        __syncthreads();   // protect s_tc/s_red before next list entry
    }
}

__global__ void yolo_finalize_kernel(const float* __restrict__ acc,
                                     const int* __restrict__ valid_cnt,
                                     float* __restrict__ out)
{
    if (threadIdx.x == 0 && blockIdx.x == 0) {
        float n_obj   = acc[0 * STR];
        float n_noobj = acc[1 * STR];
        float noobj_loss = acc[2 * STR] / n_noobj;
        float obj_loss   = acc[3 * STR] / n_obj;
        float xy_bce     = acc[4 * STR] / (n_obj * 2.0f);
        float wh_mse     = acc[5 * STR] / (n_obj * 2.0f);
        float box_loss   = xy_bce + wh_mse + acc[6 * STR] / n_obj;
        float class_loss = acc[7 * STR] / n_obj;
        float n_valid    = (float)(*valid_cnt);
        float seg_loss   = acc[8 * STR] / (n_valid + 1e-9f);
        float box_l   = 8.0f * box_loss;
        float obj_l   = 2.0f * obj_loss;
        float noobj_l = 4.0f * noobj_loss;
        float cls_l   = 1.0f * class_loss;
        float seg_l   = 10.0f * seg_loss;
        out[0] = box_l;
        out[1] = obj_l;
        out[2] = noobj_l;
        out[3] = cls_l;
        out[4] = seg_l;
        out[5] = box_l + obj_l + noobj_l + cls_l + seg_l;
    }
}

extern "C" void kernel_launch(void* const* d_in, const int* in_sizes, int n_in,
                              void* d_out, int out_size, void* d_ws, size_t ws_size,
                              hipStream_t stream) {
    const float* preds   = (const float*)d_in[0];
    const float* target  = (const float*)d_in[1];
    const float* anchors = (const float*)d_in[2];
    const float* protos  = (const float*)d_in[3];
    const float* masks   = (const float*)d_in[4];
    // d_in[5] = num_classes (80), d_in[6] = num_masks (32) — hard-coded.

    float* acc       = (float*)d_ws;
    int*   valid_cnt = (int*)((char*)d_ws + 10 * STR * sizeof(float));
    int*   valid_list= (int*)((char*)d_ws + 11 * STR * sizeof(float));
    float* out       = (float*)d_out;

    // zero accumulators + counter (one small async fill; ws is poisoned 0xAA)
    hipMemsetAsync(d_ws, 0, 11 * STR * sizeof(float), stream);

    const int ablocks = (NCELL + 255) / 256;  // 8
    yolo_cell_kernel<<<ablocks, 256, 0, stream>>>(preds, target, anchors,
                                                  acc, valid_cnt, valid_list);
    yolo_seg_kernel<<<SEG_BLOCKS, 256, 0, stream>>>(preds, target, protos, masks,
                                                    valid_cnt, valid_list, acc);
    yolo_finalize_kernel<<<1, 64, 0, stream>>>(acc, valid_cnt, out);
}

// Round 3
// 94.670 us; speedup vs baseline: 1.0743x; 1.0640x over previous
//
#include <hip/hip_runtime.h>
#include <math.h>

// Problem constants (fixed by setup_inputs in the reference)
#define N_  4
#define A_  3
#define S_  13
#define NC_ 80
#define NM_ 32
#define G_  16
#define H_  104
#define W_  104
#define CH_ (5 + NC_ + NM_)   // 117
#define HW_ (H_ * W_)
#define NCELL (N_ * A_ * S_ * S_)  // 2028

#define MAIN_BLOCKS 64
#define PROW 16   // floats per partial row (16*4 = 64B; rows padded)
// d_ws layout: partials[MAIN_BLOCKS][PROW] floats.
// slots 0..7 (valid only for rows 0..7): n_obj, n_noobj, noobj_bce, obj_bce,
//                                        xy_bce, wh_mse, one_minus_giou, nll
// slots 8..9 (all rows): seg_sum, n_valid
// All written UNCONDITIONALLY by their owning block -> no memset needed
// (d_ws is poisoned 0xAA before every launch; we never read uninitialized).

__device__ __forceinline__ float bce_logits(float x, float z) {
    return fmaxf(x, 0.0f) - x * z + log1pf(expf(-fabsf(x)));
}

__device__ __forceinline__ float sigmoidf(float x) {
    return 1.0f / (1.0f + expf(-x));
}

__device__ __forceinline__ float giou_fn(float cx1, float cy1, float w1, float h1,
                                         float cx2, float cy2, float w2, float h2) {
    const float eps = 1e-9f;
    float b1x1 = cx1 - w1 * 0.5f, b1y1 = cy1 - h1 * 0.5f;
    float b1x2 = cx1 + w1 * 0.5f, b1y2 = cy1 + h1 * 0.5f;
    float b2x1 = cx2 - w2 * 0.5f, b2y1 = cy2 - h2 * 0.5f;
    float b2x2 = cx2 + w2 * 0.5f, b2y2 = cy2 + h2 * 0.5f;
    float a1 = fmaxf(b1x2 - b1x1, 0.0f) * fmaxf(b1y2 - b1y1, 0.0f) + eps;
    float a2 = fmaxf(b2x2 - b2x1, 0.0f) * fmaxf(b2y2 - b2y1, 0.0f) + eps;
    float iw = fmaxf(fminf(b1x2, b2x2) - fmaxf(b1x1, b2x1), 0.0f);
    float ih = fmaxf(fminf(b1y2, b2y2) - fmaxf(b1y1, b2y1), 0.0f);
    float inter = iw * ih + eps;
    float uni   = a1 + a2 - inter + eps;
    float iou   = inter / uni;
    float cw = fmaxf(b1x2, b2x2) - fminf(b1x1, b2x1);
    float ch = fmaxf(b1y2, b2y2) - fminf(b1y1, b2y1);
    float carea = cw * ch + eps;
    return iou - (carea - uni) / carea;
}

// box pixel bounds for a cell; returns area, sets lo/hi
__device__ __forceinline__ int region_bounds(const float* t, int i, int j,
                                             int& lox, int& loy, int& ncols, int& nrows) {
    float bx = (t[0] + (float)j) * ((float)W_ / (float)S_);
    float by = (t[1] + (float)i) * ((float)H_ / (float)S_);
    float bw = t[2] * ((float)W_ / (float)S_);
    float bh = t[3] * ((float)H_ / (float)S_);
    int x1 = (int)floorf(bx - bw * 0.5f);
    int x2 = (int)floorf(bx + bw * 0.5f);
    int y1 = (int)floorf(by - bh * 0.5f);
    int y2 = (int)floorf(by + bh * 0.5f);
    lox = max(x1, 0); loy = max(y1, 0);
    ncols = max(min(x2, W_) - lox, 0);
    nrows = max(min(y2, H_) - loy, 0);
    return nrows * ncols;
}

// ---------------------------------------------------------------------------
// ONE main kernel, 64 blocks x 256 threads, 2 independent phases:
//  Phase 1 (blocks 0..7): thread-per-cell scalar losses -> block partials.
//  Phase 2 (all blocks): seg BCE over strided cell share, LDS compaction,
//                        block-cooperative region loops -> block partials.
// No global atomics anywhere.
// ---------------------------------------------------------------------------
__global__ __launch_bounds__(256) void yolo_main_kernel(
    const float* __restrict__ preds,    // (N,A,S,S,117)
    const float* __restrict__ target,   // (N,A,S,S,7)
    const float* __restrict__ anchors,  // (A,2)
    const float* __restrict__ protos,   // (N,32,H,W)
    const float* __restrict__ masks,    // (N,16,H,W)
    float* __restrict__ partials)
{
    const int b   = blockIdx.x;
    const int tid = threadIdx.x;

    __shared__ float s_tc[NM_];
    __shared__ float s_w[4][8];     // phase-1 cross-wave
    __shared__ float s_red[4];      // phase-2 cross-wave
    __shared__ int   s_list[40];
    __shared__ int   s_nvalid;

    // ======================= Phase 1: scalar losses ========================
    if (b < 8) {
        const int cell = b * 256 + tid;
        float v0 = 0.f, v1 = 0.f, v2 = 0.f, v3 = 0.f,
              v4 = 0.f, v5 = 0.f, v6 = 0.f, v7 = 0.f;

        if (cell < NCELL) {
            const int a = (cell / (S_ * S_)) % A_;
            const float* t = target + (size_t)cell * 7;
            const float* p = preds  + (size_t)cell * CH_;
            const float conf_t = t[4];
            const float x = p[4];

            if (conf_t == 0.0f) {
                v1 = 1.0f;
                v2 = bce_logits(x, 0.0f);
            } else if (conf_t == 1.0f) {
                v0 = 1.0f;
                float tx = t[0], ty = t[1], tw = t[2], th = t[3];
                float aw = anchors[a * 2 + 0], ah = anchors[a * 2 + 1];
                float sx = sigmoidf(p[0]);
                float sy = sigmoidf(p[1]);
                float pw = expf(p[2]) * aw;
                float ph = expf(p[3]) * ah;
                float giou = giou_fn(sx, sy, pw, ph, tx, ty, tw, th);
                v3 = bce_logits(x, fmaxf(giou, 0.0f));
                v4 = bce_logits(sx, tx) + bce_logits(sy, ty);
                float twl = logf(1e-16f + tw / aw);
                float thl = logf(1e-16f + th / ah);
                float dw = p[2] - twl, dh = p[3] - thl;
                v5 = dw * dw + dh * dh;
                v6 = 1.0f - giou;

                // 80-way log-softmax NLL, serial per obj thread (few of them)
                float mx = -1e30f;
                #pragma unroll 8
                for (int c = 0; c < NC_; ++c) mx = fmaxf(mx, p[5 + c]);
                float se = 0.0f;
                #pragma unroll 8
                for (int c = 0; c < NC_; ++c) se += expf(p[5 + c] - mx);
                int label = (int)t[5];
                v7 = (mx + logf(se)) - p[5 + label];
            }
        }

        #pragma unroll
        for (int o = 32; o > 0; o >>= 1) {
            v0 += __shfl_xor(v0, o, 64);  v1 += __shfl_xor(v1, o, 64);
            v2 += __shfl_xor(v2, o, 64);  v3 += __shfl_xor(v3, o, 64);
            v4 += __shfl_xor(v4, o, 64);  v5 += __shfl_xor(v5, o, 64);
            v6 += __shfl_xor(v6, o, 64);  v7 += __shfl_xor(v7, o, 64);
        }
        if ((tid & 63) == 0) {
            int w = tid >> 6;
            s_w[w][0] = v0; s_w[w][1] = v1; s_w[w][2] = v2; s_w[w][3] = v3;
            s_w[w][4] = v4; s_w[w][5] = v5; s_w[w][6] = v6; s_w[w][7] = v7;
        }
        __syncthreads();
        if (tid < 8) {
            partials[b * PROW + tid] =
                s_w[0][tid] + s_w[1][tid] + s_w[2][tid] + s_w[3][tid];
        }
        __syncthreads();   // s_w dead after this; keep LDS reuse safe
    }

    // ================== Phase 2: segmentation BCE ==========================
    // Block b owns cells { c : c % 64 == b }. <=32 cells; compact into LDS.
    if (tid == 0) s_nvalid = 0;
    __syncthreads();
    if (tid < 32) {
        int c = tid * 64 + b;
        if (c < NCELL) {
            const float* t = target + (size_t)c * 7;
            if (t[4] == 1.0f) {
                int lox, loy, ncols, nrows;
                int area = region_bounds(t, (c / S_) % S_, c % S_,
                                         lox, loy, ncols, nrows);
                if (area > 0) {
                    int k = atomicAdd(&s_nvalid, 1);   // LDS atomic
                    s_list[k] = c;
                }
            }
        }
    }
    __syncthreads();
    const int nv = s_nvalid;
    float block_seg = 0.0f;   // only thread 0's copy matters

    for (int ii = 0; ii < nv; ++ii) {
        const int cell = s_list[ii];
        const int j = cell % S_;
        const int i = (cell / S_) % S_;
        const int n = cell / (A_ * S_ * S_);
        const float* t = target + (size_t)cell * 7;
        const float* p = preds  + (size_t)cell * CH_;

        int lox, loy, ncols, nrows;
        int area = region_bounds(t, i, j, lox, loy, ncols, nrows);

        if (tid < NM_) s_tc[tid] = tanhf(p[5 + NC_ + tid]);
        __syncthreads();

        int id = (int)t[6];
        id = min(max(id, 0), G_ - 1);
        const float* tm = masks  + ((size_t)(n * G_ + id)) * HW_;
        const float* pr = protos + (size_t)n * NM_ * HW_;

        float lsum = 0.0f;
        for (int px = tid; px < area; px += 256) {
            int h = loy + px / ncols;
            int w = lox + px % ncols;
            int off = h * W_ + w;
            float inst = 0.0f;
            #pragma unroll
            for (int m = 0; m < NM_; ++m)
                inst += s_tc[m] * pr[m * HW_ + off];
            lsum += bce_logits(inst, tm[off]);
        }

        #pragma unroll
        for (int o = 32; o > 0; o >>= 1) lsum += __shfl_xor(lsum, o, 64);
        if ((tid & 63) == 0) s_red[tid >> 6] = lsum;
        __syncthreads();
        if (tid == 0) {
            float tot = s_red[0] + s_red[1] + s_red[2] + s_red[3];
            block_seg += tot / fmaxf((float)area, 1.0f);
        }
        __syncthreads();   // protect s_tc/s_red before next cell
    }

    if (tid == 0) {
        partials[b * PROW + 8] = block_seg;
        partials[b * PROW + 9] = (float)nv;
    }
}

// ---------------------------------------------------------------------------
// Finalize: 1 block, 64 threads. Thread t reads row t's partials; wave
// shuffle-reduce; lane 0 writes the 6 outputs.
// ---------------------------------------------------------------------------
__global__ __launch_bounds__(64) void yolo_finalize_kernel(
    const float* __restrict__ partials,
    float* __restrict__ out)
{
    const int t = threadIdx.x;
    float s0 = 0.f, s1 = 0.f, s2 = 0.f, s3 = 0.f,
          s4 = 0.f, s5 = 0.f, s6 = 0.f, s7 = 0.f, s8 = 0.f, s9 = 0.f;
    if (t < 8) {
        s0 = partials[t * PROW + 0]; s1 = partials[t * PROW + 1];
        s2 = partials[t * PROW + 2]; s3 = partials[t * PROW + 3];
        s4 = partials[t * PROW + 4]; s5 = partials[t * PROW + 5];
        s6 = partials[t * PROW + 6]; s7 = partials[t * PROW + 7];
    }
    s8 = partials[t * PROW + 8];
    s9 = partials[t * PROW + 9];

    #pragma unroll
    for (int o = 32; o > 0; o >>= 1) {
        s0 += __shfl_xor(s0, o, 64);  s1 += __shfl_xor(s1, o, 64);
        s2 += __shfl_xor(s2, o, 64);  s3 += __shfl_xor(s3, o, 64);
        s4 += __shfl_xor(s4, o, 64);  s5 += __shfl_xor(s5, o, 64);
        s6 += __shfl_xor(s6, o, 64);  s7 += __shfl_xor(s7, o, 64);
        s8 += __shfl_xor(s8, o, 64);  s9 += __shfl_xor(s9, o, 64);
    }

    if (t == 0) {
        float n_obj   = s0;
        float n_noobj = s1;
        float noobj_loss = s2 / n_noobj;
        float obj_loss   = s3 / n_obj;
        float xy_bce     = s4 / (n_obj * 2.0f);
        float wh_mse     = s5 / (n_obj * 2.0f);
        float box_loss   = xy_bce + wh_mse + s6 / n_obj;
        float class_loss = s7 / n_obj;
        float seg_loss   = s8 / (s9 + 1e-9f);
        float box_l   = 8.0f * box_loss;
        float obj_l   = 2.0f * obj_loss;
        float noobj_l = 4.0f * noobj_loss;
        float cls_l   = 1.0f * class_loss;
        float seg_l   = 10.0f * seg_loss;
        out[0] = box_l;
        out[1] = obj_l;
        out[2] = noobj_l;
        out[3] = cls_l;
        out[4] = seg_l;
        out[5] = box_l + obj_l + noobj_l + cls_l + seg_l;
    }
}

extern "C" void kernel_launch(void* const* d_in, const int* in_sizes, int n_in,
                              void* d_out, int out_size, void* d_ws, size_t ws_size,
                              hipStream_t stream) {
    const float* preds   = (const float*)d_in[0];
    const float* target  = (const float*)d_in[1];
    const float* anchors = (const float*)d_in[2];
    const float* protos  = (const float*)d_in[3];
    const float* masks   = (const float*)d_in[4];
    // d_in[5] = num_classes (80), d_in[6] = num_masks (32) — hard-coded.

    float* partials = (float*)d_ws;
    float* out      = (float*)d_out;

    yolo_main_kernel<<<MAIN_BLOCKS, 256, 0, stream>>>(preds, target, anchors,
                                                      protos, masks, partials);
    yolo_finalize_kernel<<<1, 64, 0, stream>>>(partials, out);
}